// Round 8
// baseline (274.771 us; speedup 1.0000x reference)
//
#include <hip/hip_runtime.h>
#include <hip/hip_bf16.h>

#define IN_FEATS 128
#define OUT_FEATS 64
#define HB_D 128          // dst histogram/fill slices
#define HB_S 64           // src histogram slices
#define PB 128            // prefix_scan block threads (PB words = 512 nodes)
#define NBMAX 128         // max chain blocks
#define MAX_WORDS 12544   // >= (N+3)/4 for N=50000 (u8-packed histogram, 50KB LDS)
#define SMEM_U32 16640    // K1 union: max(hist 12500 u32, proj 8192 W + 64*132 X floats)
#define PROJ_NODES 64
#define XPAD 4

static inline char* align_up(char* p, size_t a) {
    return (char*)(((uintptr_t)p + a - 1) & ~(uintptr_t)(a - 1));
}

// ---- bf16 helpers (RNE pack, shift unpack; math always fp32) ----
__device__ __forceinline__ unsigned pack_bf16(float a, float b) {
    unsigned ua = __float_as_uint(a), ub = __float_as_uint(b);
    ua = (ua + 0x7fffu + ((ua >> 16) & 1u)) >> 16;
    ub = (ub + 0x7fffu + ((ub >> 16) & 1u)) >> 16;
    return ua | (ub << 16);
}
__device__ __forceinline__ float bf16_lo(unsigned u) { return __uint_as_float(u << 16); }
__device__ __forceinline__ float bf16_hi(unsigned u) { return __uint_as_float(u & 0xffff0000u); }

// ================= K1: fused histogram (192 blocks) + projection (782 blocks) ==========
// blocks [0, HB_D)         : u8-packed LDS histogram of dst slice b
// blocks [HB_D, HB_D+HB_S) : u8-packed LDS histogram of src slice b-HB_D
// blocks [HB_D+HB_S, ...)  : proj y0 = bf16(X @ W), 64 nodes per block
// block 0 additionally zeroes the chain/ticket state for K2.
__global__ __launch_bounds__(1024)
void hist_proj_kernel(const int* __restrict__ src, const int* __restrict__ dst,
                      const float* __restrict__ X, const float* __restrict__ W,
                      unsigned* __restrict__ partial, uint2* __restrict__ Y,
                      int* __restrict__ chain, int* __restrict__ ticket,
                      int N, int E, int slice_d, int slice_s, int words) {
    __shared__ unsigned smem[SMEM_U32];
    int tid = (int)threadIdx.x;
    int b = (int)blockIdx.x;

    if (b == 0) {   // zero chain state for the chained-scan kernel (K2 runs after K1)
        if (tid <= NBMAX) chain[tid] = 0;
        if (tid == NBMAX + 1) *ticket = 0;
    }

    if (b < HB_D + HB_S) {
        // ---------------- histogram path (u8 packed: 4 nodes per u32) ----------------
        unsigned* h = smem;
        for (int w = tid; w < words; w += 1024) h[w] = 0u;
        __syncthreads();
        const int* __restrict__ keys;
        int sb, se;
        if (b < HB_D) { keys = dst; sb = b * slice_d; se = min(sb + slice_d, E); }
        else          { keys = src; sb = (b - HB_D) * slice_s; se = min(sb + slice_s, E); }
        for (int i = sb + tid * 4; i < se; i += 1024 * 4) {
            if (i + 3 < se) {
                int4 k4 = *reinterpret_cast<const int4*>(keys + i);
                atomicAdd(&h[k4.x >> 2], 1u << ((k4.x & 3) * 8));
                atomicAdd(&h[k4.y >> 2], 1u << ((k4.y & 3) * 8));
                atomicAdd(&h[k4.z >> 2], 1u << ((k4.z & 3) * 8));
                atomicAdd(&h[k4.w >> 2], 1u << ((k4.w & 3) * 8));
            } else {
                for (int j = i; j < se; ++j) {
                    int k = keys[j];
                    atomicAdd(&h[k >> 2], 1u << ((k & 3) * 8));
                }
            }
        }
        __syncthreads();
        unsigned* __restrict__ outp = partial + (size_t)b * words;
        for (int w = tid; w < words; w += 1024) outp[w] = h[w];
    } else {
        // ---------------- projection path: 64 nodes, 16 threads/node x 4 cols --------
        float* w_s = (float*)smem;                                     // 8192 floats
        float (*x_s)[IN_FEATS + XPAD] = (float (*)[IN_FEATS + XPAD])(w_s + IN_FEATS * OUT_FEATS);
        for (int i = tid; i < IN_FEATS * OUT_FEATS / 4; i += 1024)
            reinterpret_cast<float4*>(w_s)[i] = reinterpret_cast<const float4*>(W)[i];
        int base = (b - (HB_D + HB_S)) * PROJ_NODES;
        for (int i = tid; i < PROJ_NODES * IN_FEATS / 4; i += 1024) {
            int r = i >> 5;            // 32 float4 per row
            int c = (i & 31) * 4;
            int node = base + r;
            float4 v = (node < N) ? *reinterpret_cast<const float4*>(X + (size_t)node * IN_FEATS + c)
                                  : make_float4(0.f, 0.f, 0.f, 0.f);
            *reinterpret_cast<float4*>(&x_s[r][c]) = v;
        }
        __syncthreads();
        int r = tid >> 4;                   // local node 0..63
        int jj = (tid & 15) * 4;            // col base
        float4 a = make_float4(0.f, 0.f, 0.f, 0.f);
        for (int k = 0; k < IN_FEATS; k += 4) {
            float4 x = *reinterpret_cast<const float4*>(&x_s[r][k]);
#pragma unroll
            for (int q = 0; q < 4; ++q) {
                float4 w = *reinterpret_cast<const float4*>(&w_s[(k + q) * OUT_FEATS + jj]);
                float e = (q == 0) ? x.x : (q == 1) ? x.y : (q == 2) ? x.z : x.w;
                a.x = fmaf(e, w.x, a.x); a.y = fmaf(e, w.y, a.y);
                a.z = fmaf(e, w.z, a.z); a.w = fmaf(e, w.w, a.w);
            }
        }
        int node = base + r;
        if (node < N) {
            uint2 o; o.x = pack_bf16(a.x, a.y); o.y = pack_bf16(a.z, a.w);
            Y[(size_t)node * (OUT_FEATS / 4) + (jj >> 2)] = o;
        }
    }
}

// ========== K2: chained scan — per-word prefixes, rowptr, norms, all in one ============
// virtual block id from ticket guarantees lookback targets are already resident.
__global__ __launch_bounds__(PB)
void prefix_scan_kernel(const unsigned* __restrict__ partial, unsigned* __restrict__ pprefix,
                        int* __restrict__ rowptr, float* __restrict__ normS,
                        float* __restrict__ normD, int* __restrict__ chain,
                        int* __restrict__ ticket, int N, int words) {
    __shared__ int s_vbid, s_base;
    __shared__ int buf[PB];
    int tid = (int)threadIdx.x;
    if (tid == 0) s_vbid = atomicAdd(ticket, 1);
    __syncthreads();
    int vbid = s_vbid;
    int w = vbid * PB + tid;

    unsigned run = 0, ssum = 0;
    if (w < words) {
#pragma unroll 8
        for (int b = 0; b < HB_D; ++b) {
            unsigned v = partial[(size_t)b * words + w];
            pprefix[(size_t)b * words + w] = run;   // exclusive per-node prefix (u8 lanes)
            run += v;
        }
#pragma unroll 8
        for (int b = HB_D; b < HB_D + HB_S; ++b) ssum += partial[(size_t)b * words + w];
    }
    int c0 = (int)(run & 0xffu), c1 = (int)((run >> 8) & 0xffu);
    int c2 = (int)((run >> 16) & 0xffu), c3 = (int)(run >> 24);
    int dtot = c0 + c1 + c2 + c3;

    buf[tid] = dtot;
    __syncthreads();
    for (int off = 1; off < PB; off <<= 1) {
        int t = (tid >= off) ? buf[tid - off] : 0;
        __syncthreads();
        buf[tid] += t;
        __syncthreads();
    }
    int excl = buf[tid] - dtot;
    int btot = buf[PB - 1];

    if (tid == 0) {
        int base = 0;
        if (vbid > 0) {
            int v;
            do {
                v = __hip_atomic_load(chain + vbid - 1, __ATOMIC_ACQUIRE, __HIP_MEMORY_SCOPE_AGENT);
            } while (v == 0);
            base = v - 1;
        }
        __hip_atomic_store(chain + vbid, base + btot + 1, __ATOMIC_RELEASE, __HIP_MEMORY_SCOPE_AGENT);
        s_base = base;
    }
    __syncthreads();
    int base = s_base;

    if (w < words) {
        int r0 = base + excl, r1 = r0 + c0, r2 = r1 + c1, r3 = r2 + c2;
        *reinterpret_cast<int4*>(rowptr + 4 * w) = make_int4(r0, r1, r2, r3);
        float4 nD = make_float4(rsqrtf(fmaxf((float)c0, 1.f)), rsqrtf(fmaxf((float)c1, 1.f)),
                                rsqrtf(fmaxf((float)c2, 1.f)), rsqrtf(fmaxf((float)c3, 1.f)));
        int s0 = (int)(ssum & 0xffu), s1 = (int)((ssum >> 8) & 0xffu);
        int s2 = (int)((ssum >> 16) & 0xffu), s3 = (int)(ssum >> 24);
        float4 nS = make_float4(rsqrtf(fmaxf((float)s0, 1.f)), rsqrtf(fmaxf((float)s1, 1.f)),
                                rsqrtf(fmaxf((float)s2, 1.f)), rsqrtf(fmaxf((float)s3, 1.f)));
        *reinterpret_cast<float4*>(normD + 4 * w) = nD;
        *reinterpret_cast<float4*>(normS + 4 * w) = nS;
        if (w == words - 1) rowptr[N] = r3 + c3;   // grand total
    }
}

// ========== K3: CSR fill, u8 LDS cursors seeded from precomputed per-block prefixes ====
__global__ __launch_bounds__(1024)
void fill_kernel(const int* __restrict__ src, const int* __restrict__ dst,
                 const unsigned* __restrict__ pprefix, const int* __restrict__ rowptr,
                 int* __restrict__ csr_src, int E, int slice, int words) {
    __shared__ unsigned cur[MAX_WORDS];
    int tid = (int)threadIdx.x;
    int b = (int)blockIdx.x;
    const unsigned* __restrict__ pp = pprefix + (size_t)b * words;
    for (int w = tid; w < words; w += 1024) cur[w] = pp[w];
    __syncthreads();
    int sb = b * slice;
    int se = min(sb + slice, E);
    for (int i = sb + tid * 4; i < se; i += 1024 * 4) {
        if (i + 3 < se) {
            int4 d4 = *reinterpret_cast<const int4*>(dst + i);
            int4 s4 = *reinterpret_cast<const int4*>(src + i);
            int dd[4] = {d4.x, d4.y, d4.z, d4.w};
            int ss[4] = {s4.x, s4.y, s4.z, s4.w};
#pragma unroll
            for (int j = 0; j < 4; ++j) {
                int bin = dd[j];
                unsigned sh = (unsigned)(bin & 3) * 8u;
                unsigned old = atomicAdd(&cur[bin >> 2], 1u << sh);
                int off = (int)((old >> sh) & 0xffu);
                csr_src[rowptr[bin] + off] = ss[j];
            }
        } else {
            for (int j = i; j < se; ++j) {
                int bin = dst[j];
                unsigned sh = (unsigned)(bin & 3) * 8u;
                unsigned old = atomicAdd(&cur[bin >> 2], 1u << sh);
                int off = (int)((old >> sh) & 0xffu);
                csr_src[rowptr[bin] + off] = src[j];
            }
        }
    }
}

// ================= gather hop over bf16 rows ================
// one wave/node; 16 lanes x uint2 (4 bf16) cover 64 feats; 4 edge-groups, 2x unroll.
// EPI: 0 -> bf16 out; 1 -> *vec[node], bf16 out; 2 -> *vec[node]+bias, f32 out
template <int EPI>
__global__ __launch_bounds__(256)
void gather_hop(const uint2* __restrict__ Yin, const int* __restrict__ rowptr,
                const int* __restrict__ csr_src, void* __restrict__ Yout,
                const float* __restrict__ vec, const float* __restrict__ bias,
                int N) {
    int node = blockIdx.x * 4 + ((int)threadIdx.x >> 6);
    int lane = (int)threadIdx.x & 63;
    int g = lane >> 4;
    int ci = lane & 15;
    if (node >= N) return;
    int beg = rowptr[node];
    int end = rowptr[node + 1];
    float4 acc = make_float4(0.f, 0.f, 0.f, 0.f);
    float4 acc2 = make_float4(0.f, 0.f, 0.f, 0.f);
    int k = beg + g;
    for (; k + 4 < end; k += 8) {
        int s0 = csr_src[k];
        int s1 = csr_src[k + 4];
        uint2 v0 = Yin[(size_t)s0 * (OUT_FEATS / 4) + ci];
        uint2 v1 = Yin[(size_t)s1 * (OUT_FEATS / 4) + ci];
        acc.x += bf16_lo(v0.x); acc.y += bf16_hi(v0.x);
        acc.z += bf16_lo(v0.y); acc.w += bf16_hi(v0.y);
        acc2.x += bf16_lo(v1.x); acc2.y += bf16_hi(v1.x);
        acc2.z += bf16_lo(v1.y); acc2.w += bf16_hi(v1.y);
    }
    if (k < end) {
        uint2 v = Yin[(size_t)csr_src[k] * (OUT_FEATS / 4) + ci];
        acc.x += bf16_lo(v.x); acc.y += bf16_hi(v.x);
        acc.z += bf16_lo(v.y); acc.w += bf16_hi(v.y);
    }
    acc.x += acc2.x; acc.y += acc2.y; acc.z += acc2.z; acc.w += acc2.w;
    acc.x += __shfl_xor(acc.x, 16); acc.y += __shfl_xor(acc.y, 16);
    acc.z += __shfl_xor(acc.z, 16); acc.w += __shfl_xor(acc.w, 16);
    acc.x += __shfl_xor(acc.x, 32); acc.y += __shfl_xor(acc.y, 32);
    acc.z += __shfl_xor(acc.z, 32); acc.w += __shfl_xor(acc.w, 32);
    if (g == 0) {
        if (EPI == 1) {
            float sc = vec[node];
            acc.x *= sc; acc.y *= sc; acc.z *= sc; acc.w *= sc;
        }
        if (EPI == 2) {
            float sc = vec[node];
            float4 bb = *reinterpret_cast<const float4*>(bias + ci * 4);
            acc.x = fmaf(acc.x, sc, bb.x); acc.y = fmaf(acc.y, sc, bb.y);
            acc.z = fmaf(acc.z, sc, bb.z); acc.w = fmaf(acc.w, sc, bb.w);
            reinterpret_cast<float4*>(Yout)[(size_t)node * (OUT_FEATS / 4) + ci] = acc;
        } else {
            uint2 o;
            o.x = pack_bf16(acc.x, acc.y);
            o.y = pack_bf16(acc.z, acc.w);
            reinterpret_cast<uint2*>(Yout)[(size_t)node * (OUT_FEATS / 4) + ci] = o;
        }
    }
}

extern "C" void kernel_launch(void* const* d_in, const int* in_sizes, int n_in,
                              void* d_out, int out_size, void* d_ws, size_t ws_size,
                              hipStream_t stream) {
    const float* features = (const float*)d_in[0];
    const int*   src      = (const int*)d_in[1];
    const int*   dst      = (const int*)d_in[2];
    const float* weight   = (const float*)d_in[3];
    const float* bias     = (const float*)d_in[4];

    const int N = in_sizes[0] / IN_FEATS;   // 50000
    const int E = in_sizes[1];              // 640000
    const int words = (N + 3) / 4;          // 12500 (u8-packed)
    const int NB = (words + PB - 1) / PB;   // 98 chain blocks
    const int slice_d = (((E + HB_D - 1) / HB_D) + 3) & ~3;  // 5000
    const int slice_s = (((E + HB_S - 1) / HB_S) + 3) & ~3;  // 10000
    const int projBlocks = (N + PROJ_NODES - 1) / PROJ_NODES; // 782

    char* p = (char*)d_ws;
    float* normS   = (float*)p;  p = align_up(p + sizeof(float) * (N + 4), 256);
    float* normD   = (float*)p;  p = align_up(p + sizeof(float) * (N + 4), 256);
    uint2* y0      = (uint2*)p;  p = align_up(p + sizeof(uint2) * (size_t)N * (OUT_FEATS / 4), 256);
    uint2* y1      = (uint2*)p;  p = align_up(p + sizeof(uint2) * (size_t)N * (OUT_FEATS / 4), 256);
    int*   rowptr  = (int*)p;    p = align_up(p + sizeof(int) * (N + 8), 256);
    int*   chain   = (int*)p;    p = align_up(p + sizeof(int) * (NBMAX + 2), 256);
    int*   ticket  = (int*)p;    p = align_up(p + sizeof(int) * 4, 256);
    int*   csr_src = (int*)p;    p = align_up(p + sizeof(int) * (size_t)E, 256);
    unsigned* partial = (unsigned*)p;  p = align_up(p + sizeof(unsigned) * (size_t)(HB_D + HB_S) * words, 256);
    unsigned* pprefix = (unsigned*)p;  p = align_up(p + sizeof(unsigned) * (size_t)HB_D * words, 256);

    float* out = (float*)d_out;

    // K1: u8 histograms (192 blocks) + projection (782 blocks) + chain-state zeroing
    hist_proj_kernel<<<HB_D + HB_S + projBlocks, 1024, 0, stream>>>(
        src, dst, features, weight, partial, y0, chain, ticket, N, E, slice_d, slice_s, words);
    // K2: chained scan — per-block prefixes, rowptr, norms in one pass
    prefix_scan_kernel<<<NB, PB, 0, stream>>>(partial, pprefix, rowptr, normS, normD,
                                              chain, ticket, N, words);
    // K3: CSR fill, zero global atomics
    fill_kernel<<<HB_D, 1024, 0, stream>>>(src, dst, pprefix, rowptr, csr_src, E, slice_d, words);

    const int hop_blocks = (N + 3) / 4;
    // hop 1: y1 = A y0                    (bf16 -> bf16)
    gather_hop<0><<<hop_blocks, 256, 0, stream>>>(y0, rowptr, csr_src, (void*)y1, nullptr, nullptr, N);
    // hop 2: y0 = normS .* (A y1)         (bf16 -> bf16)
    gather_hop<1><<<hop_blocks, 256, 0, stream>>>(y1, rowptr, csr_src, (void*)y0, normS, nullptr, N);
    // hop 3: out = normD .* (A y0) + bias (bf16 -> f32)
    gather_hop<2><<<hop_blocks, 256, 0, stream>>>(y0, rowptr, csr_src, (void*)out, normD, bias, N);
}

// Round 9
// 125.421 us; speedup vs baseline: 2.1908x; 2.1908x over previous
//
#include <hip/hip_runtime.h>
#include <hip/hip_bf16.h>

#define IN_FEATS 128
#define OUT_FEATS 64
#define HB_D 128          // dst histogram/fill slices
#define HB_S 64           // src histogram slices
#define PB 256            // prefix/scan block threads (PB words = 1024 nodes)
#define MAX_WORDS 12544   // >= (N+3)/4 for N=50000 (u8-packed histogram, 50KB LDS)
#define SMEM_U32 16640    // K1 union: max(hist 12500 u32, proj 8192 W + 64*132 X floats)
#define PROJ_NODES 64
#define XPAD 4

static inline char* align_up(char* p, size_t a) {
    return (char*)(((uintptr_t)p + a - 1) & ~(uintptr_t)(a - 1));
}

// ---- bf16 helpers (RNE pack, shift unpack; math always fp32) ----
__device__ __forceinline__ unsigned pack_bf16(float a, float b) {
    unsigned ua = __float_as_uint(a), ub = __float_as_uint(b);
    ua = (ua + 0x7fffu + ((ua >> 16) & 1u)) >> 16;
    ub = (ub + 0x7fffu + ((ub >> 16) & 1u)) >> 16;
    return ua | (ub << 16);
}
__device__ __forceinline__ float bf16_lo(unsigned u) { return __uint_as_float(u << 16); }
__device__ __forceinline__ float bf16_hi(unsigned u) { return __uint_as_float(u & 0xffff0000u); }

// ================= K1: fused histogram (192 blocks) + projection (782 blocks) ==========
// blocks [0, HB_D)         : u8-packed LDS histogram of dst slice b
// blocks [HB_D, HB_D+HB_S) : u8-packed LDS histogram of src slice b-HB_D
// blocks [HB_D+HB_S, ...)  : proj y0 = bf16(X @ W), 64 nodes per block
__global__ __launch_bounds__(1024)
void hist_proj_kernel(const int* __restrict__ src, const int* __restrict__ dst,
                      const float* __restrict__ X, const float* __restrict__ W,
                      unsigned* __restrict__ partial, uint2* __restrict__ Y,
                      int N, int E, int slice_d, int slice_s, int words) {
    __shared__ unsigned smem[SMEM_U32];
    int tid = (int)threadIdx.x;
    int b = (int)blockIdx.x;

    if (b < HB_D + HB_S) {
        // ---------------- histogram path (u8 packed: 4 nodes per u32) ----------------
        unsigned* h = smem;
        for (int w = tid; w < words; w += 1024) h[w] = 0u;
        __syncthreads();
        const int* __restrict__ keys;
        int sb, se;
        if (b < HB_D) { keys = dst; sb = b * slice_d; se = min(sb + slice_d, E); }
        else          { keys = src; sb = (b - HB_D) * slice_s; se = min(sb + slice_s, E); }
        for (int i = sb + tid * 4; i < se; i += 1024 * 4) {
            if (i + 3 < se) {
                int4 k4 = *reinterpret_cast<const int4*>(keys + i);
                atomicAdd(&h[k4.x >> 2], 1u << ((k4.x & 3) * 8));
                atomicAdd(&h[k4.y >> 2], 1u << ((k4.y & 3) * 8));
                atomicAdd(&h[k4.z >> 2], 1u << ((k4.z & 3) * 8));
                atomicAdd(&h[k4.w >> 2], 1u << ((k4.w & 3) * 8));
            } else {
                for (int j = i; j < se; ++j) {
                    int k = keys[j];
                    atomicAdd(&h[k >> 2], 1u << ((k & 3) * 8));
                }
            }
        }
        __syncthreads();
        unsigned* __restrict__ outp = partial + (size_t)b * words;
        for (int w = tid; w < words; w += 1024) outp[w] = h[w];
    } else {
        // ---------------- projection path: 64 nodes, 16 threads/node x 4 cols --------
        float* w_s = (float*)smem;                                     // 8192 floats
        float (*x_s)[IN_FEATS + XPAD] = (float (*)[IN_FEATS + XPAD])(w_s + IN_FEATS * OUT_FEATS);
        for (int i = tid; i < IN_FEATS * OUT_FEATS / 4; i += 1024)
            reinterpret_cast<float4*>(w_s)[i] = reinterpret_cast<const float4*>(W)[i];
        int base = (b - (HB_D + HB_S)) * PROJ_NODES;
        for (int i = tid; i < PROJ_NODES * IN_FEATS / 4; i += 1024) {
            int r = i >> 5;            // 32 float4 per row
            int c = (i & 31) * 4;
            int node = base + r;
            float4 v = (node < N) ? *reinterpret_cast<const float4*>(X + (size_t)node * IN_FEATS + c)
                                  : make_float4(0.f, 0.f, 0.f, 0.f);
            *reinterpret_cast<float4*>(&x_s[r][c]) = v;
        }
        __syncthreads();
        int r = tid >> 4;                   // local node 0..63
        int jj = (tid & 15) * 4;            // col base
        float4 a = make_float4(0.f, 0.f, 0.f, 0.f);
        for (int k = 0; k < IN_FEATS; k += 4) {
            float4 x = *reinterpret_cast<const float4*>(&x_s[r][k]);
#pragma unroll
            for (int q = 0; q < 4; ++q) {
                float4 w = *reinterpret_cast<const float4*>(&w_s[(k + q) * OUT_FEATS + jj]);
                float e = (q == 0) ? x.x : (q == 1) ? x.y : (q == 2) ? x.z : x.w;
                a.x = fmaf(e, w.x, a.x); a.y = fmaf(e, w.y, a.y);
                a.z = fmaf(e, w.z, a.z); a.w = fmaf(e, w.w, a.w);
            }
        }
        int node = base + r;
        if (node < N) {
            uint2 o; o.x = pack_bf16(a.x, a.y); o.y = pack_bf16(a.z, a.w);
            Y[(size_t)node * (OUT_FEATS / 4) + (jj >> 2)] = o;
        }
    }
}

// ========== K2: per-word prefixes (register-batched, no inter-block deps) ==============
// thread w: exclusive prefix of dst-partials across HB_D blocks -> pprefix;
// final packed counts -> cntDp/cntSp (u32 = 4 u8 lanes); block emits chunk sum to bsums.
__global__ __launch_bounds__(PB)
void prefix_kernel(const unsigned* __restrict__ partial, unsigned* __restrict__ pprefix,
                   unsigned* __restrict__ cntDp, unsigned* __restrict__ cntSp,
                   int* __restrict__ bsums, int words) {
    __shared__ int red[PB];
    int tid = (int)threadIdx.x;
    int w = (int)blockIdx.x * PB + tid;
    int dtot = 0;
    if (w < words) {
        unsigned run = 0;
        for (int bb = 0; bb < HB_D; bb += 16) {
            unsigned v[16], pfx[16];
#pragma unroll
            for (int i = 0; i < 16; ++i) v[i] = partial[(size_t)(bb + i) * words + w];
#pragma unroll
            for (int i = 0; i < 16; ++i) { pfx[i] = run; run += v[i]; }
#pragma unroll
            for (int i = 0; i < 16; ++i) pprefix[(size_t)(bb + i) * words + w] = pfx[i];
        }
        unsigned ssum = 0;
        for (int bb = HB_D; bb < HB_D + HB_S; bb += 16) {
            unsigned v[16];
#pragma unroll
            for (int i = 0; i < 16; ++i) v[i] = partial[(size_t)(bb + i) * words + w];
#pragma unroll
            for (int i = 0; i < 16; ++i) ssum += v[i];
        }
        cntDp[w] = run;
        cntSp[w] = ssum;
        dtot = (int)((run & 0xffu) + ((run >> 8) & 0xffu) + ((run >> 16) & 0xffu) + (run >> 24));
    }
    red[tid] = dtot;
    __syncthreads();
    for (int off = PB / 2; off > 0; off >>= 1) {
        if (tid < off) red[tid] += red[tid + off];
        __syncthreads();
    }
    if (tid == 0) bsums[blockIdx.x] = red[0];
}

// ========== K3: rowptr + norms; wave0 re-scans the (<=64) chunk sums inline ============
__global__ __launch_bounds__(PB)
void scan_apply(const unsigned* __restrict__ cntDp, const unsigned* __restrict__ cntSp,
                const int* __restrict__ bsums, int* __restrict__ rowptr,
                float* __restrict__ normS, float* __restrict__ normD,
                int N, int words, int NB) {
    __shared__ int tsum[PB];
    __shared__ int sboff;
    int tid = (int)threadIdx.x;
    if (tid < 64) {                       // NB <= 64 by construction
        int v = (tid < NB) ? bsums[tid] : 0;
        int orig = v;
        for (int off = 1; off < 64; off <<= 1) {
            int t = __shfl_up(v, off);
            if (tid >= off) v += t;
        }
        if (tid == (int)blockIdx.x) sboff = v - orig;          // exclusive chunk base
        if (blockIdx.x == 0 && tid == NB - 1) rowptr[N] = v;   // grand total
    }
    __syncthreads();
    int w = (int)blockIdx.x * PB + tid;
    unsigned cd = (w < words) ? cntDp[w] : 0u;
    unsigned cs = (w < words) ? cntSp[w] : 0u;
    int c0 = (int)(cd & 0xffu), c1 = (int)((cd >> 8) & 0xffu);
    int c2 = (int)((cd >> 16) & 0xffu), c3 = (int)(cd >> 24);
    int dtot = c0 + c1 + c2 + c3;
    tsum[tid] = dtot;
    __syncthreads();
    for (int off = 1; off < PB; off <<= 1) {
        int t = (tid >= off) ? tsum[tid - off] : 0;
        __syncthreads();
        tsum[tid] += t;
        __syncthreads();
    }
    if (w < words) {
        int excl = tsum[tid] - dtot + sboff;
        int r0 = excl, r1 = r0 + c0, r2 = r1 + c1, r3 = r2 + c2;
        int base = 4 * w;
        if (base + 3 < N + 1) {  // N divisible by 4 here; int4 write covers nodes base..base+3
            *reinterpret_cast<int4*>(rowptr + base) = make_int4(r0, r1, r2, r3);
        } else {
            int r[4] = {r0, r1, r2, r3};
            for (int i = 0; i < 4 && base + i <= N; ++i) rowptr[base + i] = r[i];
        }
        float4 nD = make_float4(rsqrtf(fmaxf((float)c0, 1.f)), rsqrtf(fmaxf((float)c1, 1.f)),
                                rsqrtf(fmaxf((float)c2, 1.f)), rsqrtf(fmaxf((float)c3, 1.f)));
        int s0 = (int)(cs & 0xffu), s1 = (int)((cs >> 8) & 0xffu);
        int s2 = (int)((cs >> 16) & 0xffu), s3 = (int)(cs >> 24);
        float4 nS = make_float4(rsqrtf(fmaxf((float)s0, 1.f)), rsqrtf(fmaxf((float)s1, 1.f)),
                                rsqrtf(fmaxf((float)s2, 1.f)), rsqrtf(fmaxf((float)s3, 1.f)));
        if (base + 3 < N) {
            *reinterpret_cast<float4*>(normD + base) = nD;
            *reinterpret_cast<float4*>(normS + base) = nS;
        } else {
            float d[4] = {nD.x, nD.y, nD.z, nD.w};
            float s[4] = {nS.x, nS.y, nS.z, nS.w};
            for (int i = 0; i < 4 && base + i < N; ++i) { normD[base + i] = d[i]; normS[base + i] = s[i]; }
        }
    }
}

// ========== K4: CSR fill, u8 LDS cursors seeded from precomputed per-block prefixes ====
__global__ __launch_bounds__(1024)
void fill_kernel(const int* __restrict__ src, const int* __restrict__ dst,
                 const unsigned* __restrict__ pprefix, const int* __restrict__ rowptr,
                 int* __restrict__ csr_src, int E, int slice, int words) {
    __shared__ unsigned cur[MAX_WORDS];
    int tid = (int)threadIdx.x;
    int b = (int)blockIdx.x;
    const unsigned* __restrict__ pp = pprefix + (size_t)b * words;
    for (int w = tid; w < words; w += 1024) cur[w] = pp[w];
    __syncthreads();
    int sb = b * slice;
    int se = min(sb + slice, E);
    for (int i = sb + tid * 4; i < se; i += 1024 * 4) {
        if (i + 3 < se) {
            int4 d4 = *reinterpret_cast<const int4*>(dst + i);
            int4 s4 = *reinterpret_cast<const int4*>(src + i);
            int dd[4] = {d4.x, d4.y, d4.z, d4.w};
            int ss[4] = {s4.x, s4.y, s4.z, s4.w};
#pragma unroll
            for (int j = 0; j < 4; ++j) {
                int bin = dd[j];
                unsigned sh = (unsigned)(bin & 3) * 8u;
                unsigned old = atomicAdd(&cur[bin >> 2], 1u << sh);
                int off = (int)((old >> sh) & 0xffu);
                csr_src[rowptr[bin] + off] = ss[j];
            }
        } else {
            for (int j = i; j < se; ++j) {
                int bin = dst[j];
                unsigned sh = (unsigned)(bin & 3) * 8u;
                unsigned old = atomicAdd(&cur[bin >> 2], 1u << sh);
                int off = (int)((old >> sh) & 0xffu);
                csr_src[rowptr[bin] + off] = src[j];
            }
        }
    }
}

// ================= gather hop over bf16 rows ================
// one wave/node; 16 lanes x uint2 (4 bf16) cover 64 feats; 4 edge-groups, 2x unroll.
// EPI: 0 -> bf16 out; 1 -> *vec[node], bf16 out; 2 -> *vec[node]+bias, f32 out
template <int EPI>
__global__ __launch_bounds__(256)
void gather_hop(const uint2* __restrict__ Yin, const int* __restrict__ rowptr,
                const int* __restrict__ csr_src, void* __restrict__ Yout,
                const float* __restrict__ vec, const float* __restrict__ bias,
                int N) {
    int node = blockIdx.x * 4 + ((int)threadIdx.x >> 6);
    int lane = (int)threadIdx.x & 63;
    int g = lane >> 4;
    int ci = lane & 15;
    if (node >= N) return;
    int beg = rowptr[node];
    int end = rowptr[node + 1];
    float4 acc = make_float4(0.f, 0.f, 0.f, 0.f);
    float4 acc2 = make_float4(0.f, 0.f, 0.f, 0.f);
    int k = beg + g;
    for (; k + 4 < end; k += 8) {
        int s0 = csr_src[k];
        int s1 = csr_src[k + 4];
        uint2 v0 = Yin[(size_t)s0 * (OUT_FEATS / 4) + ci];
        uint2 v1 = Yin[(size_t)s1 * (OUT_FEATS / 4) + ci];
        acc.x += bf16_lo(v0.x); acc.y += bf16_hi(v0.x);
        acc.z += bf16_lo(v0.y); acc.w += bf16_hi(v0.y);
        acc2.x += bf16_lo(v1.x); acc2.y += bf16_hi(v1.x);
        acc2.z += bf16_lo(v1.y); acc2.w += bf16_hi(v1.y);
    }
    if (k < end) {
        uint2 v = Yin[(size_t)csr_src[k] * (OUT_FEATS / 4) + ci];
        acc.x += bf16_lo(v.x); acc.y += bf16_hi(v.x);
        acc.z += bf16_lo(v.y); acc.w += bf16_hi(v.y);
    }
    acc.x += acc2.x; acc.y += acc2.y; acc.z += acc2.z; acc.w += acc2.w;
    acc.x += __shfl_xor(acc.x, 16); acc.y += __shfl_xor(acc.y, 16);
    acc.z += __shfl_xor(acc.z, 16); acc.w += __shfl_xor(acc.w, 16);
    acc.x += __shfl_xor(acc.x, 32); acc.y += __shfl_xor(acc.y, 32);
    acc.z += __shfl_xor(acc.z, 32); acc.w += __shfl_xor(acc.w, 32);
    if (g == 0) {
        if (EPI == 1) {
            float sc = vec[node];
            acc.x *= sc; acc.y *= sc; acc.z *= sc; acc.w *= sc;
        }
        if (EPI == 2) {
            float sc = vec[node];
            float4 bb = *reinterpret_cast<const float4*>(bias + ci * 4);
            acc.x = fmaf(acc.x, sc, bb.x); acc.y = fmaf(acc.y, sc, bb.y);
            acc.z = fmaf(acc.z, sc, bb.z); acc.w = fmaf(acc.w, sc, bb.w);
            reinterpret_cast<float4*>(Yout)[(size_t)node * (OUT_FEATS / 4) + ci] = acc;
        } else {
            uint2 o;
            o.x = pack_bf16(acc.x, acc.y);
            o.y = pack_bf16(acc.z, acc.w);
            reinterpret_cast<uint2*>(Yout)[(size_t)node * (OUT_FEATS / 4) + ci] = o;
        }
    }
}

extern "C" void kernel_launch(void* const* d_in, const int* in_sizes, int n_in,
                              void* d_out, int out_size, void* d_ws, size_t ws_size,
                              hipStream_t stream) {
    const float* features = (const float*)d_in[0];
    const int*   src      = (const int*)d_in[1];
    const int*   dst      = (const int*)d_in[2];
    const float* weight   = (const float*)d_in[3];
    const float* bias     = (const float*)d_in[4];

    const int N = in_sizes[0] / IN_FEATS;   // 50000
    const int E = in_sizes[1];              // 640000
    const int words = (N + 3) / 4;          // 12500 (u8-packed)
    const int NB = (words + PB - 1) / PB;   // 49 chunks (<= 64)
    const int slice_d = (((E + HB_D - 1) / HB_D) + 3) & ~3;  // 5000
    const int slice_s = (((E + HB_S - 1) / HB_S) + 3) & ~3;  // 10000
    const int projBlocks = (N + PROJ_NODES - 1) / PROJ_NODES; // 782

    char* p = (char*)d_ws;
    float* normS   = (float*)p;  p = align_up(p + sizeof(float) * (N + 4), 256);
    float* normD   = (float*)p;  p = align_up(p + sizeof(float) * (N + 4), 256);
    uint2* y0      = (uint2*)p;  p = align_up(p + sizeof(uint2) * (size_t)N * (OUT_FEATS / 4), 256);
    uint2* y1      = (uint2*)p;  p = align_up(p + sizeof(uint2) * (size_t)N * (OUT_FEATS / 4), 256);
    int*   rowptr  = (int*)p;    p = align_up(p + sizeof(int) * (N + 8), 256);
    unsigned* cntDp = (unsigned*)p;  p = align_up(p + sizeof(unsigned) * (words + 4), 256);
    unsigned* cntSp = (unsigned*)p;  p = align_up(p + sizeof(unsigned) * (words + 4), 256);
    int*   bsums   = (int*)p;    p = align_up(p + sizeof(int) * 64, 256);
    int*   csr_src = (int*)p;    p = align_up(p + sizeof(int) * (size_t)E, 256);
    unsigned* partial = (unsigned*)p;  p = align_up(p + sizeof(unsigned) * (size_t)(HB_D + HB_S) * words, 256);
    unsigned* pprefix = (unsigned*)p;  p = align_up(p + sizeof(unsigned) * (size_t)HB_D * words, 256);

    float* out = (float*)d_out;

    // K1: u8 histograms (192 blocks) + projection (782 blocks), concurrent
    hist_proj_kernel<<<HB_D + HB_S + projBlocks, 1024, 0, stream>>>(
        src, dst, features, weight, partial, y0, N, E, slice_d, slice_s, words);
    // K2: per-word prefixes + packed counts + chunk sums (register-batched, no chaining)
    prefix_kernel<<<NB, PB, 0, stream>>>(partial, pprefix, cntDp, cntSp, bsums, words);
    // K3: rowptr + norms (inline wave0 re-scan of chunk sums)
    scan_apply<<<NB, PB, 0, stream>>>(cntDp, cntSp, bsums, rowptr, normS, normD, N, words, NB);
    // K4: CSR fill, zero global atomics
    fill_kernel<<<HB_D, 1024, 0, stream>>>(src, dst, pprefix, rowptr, csr_src, E, slice_d, words);

    const int hop_blocks = (N + 3) / 4;
    // hop 1: y1 = A y0                    (bf16 -> bf16)
    gather_hop<0><<<hop_blocks, 256, 0, stream>>>(y0, rowptr, csr_src, (void*)y1, nullptr, nullptr, N);
    // hop 2: y0 = normS .* (A y1)         (bf16 -> bf16)
    gather_hop<1><<<hop_blocks, 256, 0, stream>>>(y1, rowptr, csr_src, (void*)y0, normS, nullptr, N);
    // hop 3: out = normD .* (A y0) + bias (bf16 -> f32)
    gather_hop<2><<<hop_blocks, 256, 0, stream>>>(y0, rowptr, csr_src, (void*)out, normD, bias, N);
}

// Round 10
// 122.312 us; speedup vs baseline: 2.2465x; 1.0254x over previous
//
#include <hip/hip_runtime.h>
#include <hip/hip_bf16.h>

#define IN_FEATS 128
#define OUT_FEATS 64
#define HB_D 128          // dst histogram/fill slices
#define HB_S 64           // src histogram slices
#define PB 256            // prefix/scan block threads (PB words = 1024 nodes)
#define MAX_WORDS 12544   // >= (N+3)/4 for N=50000 (u8-packed histogram, 50KB LDS)
#define SMEM_U32 12544    // K1 union: max(hist 12500 u32, proj 8192 floats for W)
#define PROJ_NODES 256    // nodes per proj block (64 slots x 4 nodes)

static inline char* align_up(char* p, size_t a) {
    return (char*)(((uintptr_t)p + a - 1) & ~(uintptr_t)(a - 1));
}

// ---- bf16 helpers (RNE pack, shift unpack; math always fp32) ----
__device__ __forceinline__ unsigned pack_bf16(float a, float b) {
    unsigned ua = __float_as_uint(a), ub = __float_as_uint(b);
    ua = (ua + 0x7fffu + ((ua >> 16) & 1u)) >> 16;
    ub = (ub + 0x7fffu + ((ub >> 16) & 1u)) >> 16;
    return ua | (ub << 16);
}
__device__ __forceinline__ float bf16_lo(unsigned u) { return __uint_as_float(u << 16); }
__device__ __forceinline__ float bf16_hi(unsigned u) { return __uint_as_float(u & 0xffff0000u); }

// ================= K1: fused histogram (192 blocks) + projection (196 blocks) ==========
// blocks [0, HB_D)         : u8-packed LDS histogram of dst slice b
// blocks [HB_D, HB_D+HB_S) : u8-packed LDS histogram of src slice b-HB_D
// blocks [HB_D+HB_S, ...)  : proj y0 = bf16(X @ W); 256 nodes/block, 4 nodes x 4 cols
//                            per thread; X read from global (broadcast-coalesced),
//                            only W staged in LDS -> ~5x less LDS read traffic.
__global__ __launch_bounds__(1024)
void hist_proj_kernel(const int* __restrict__ src, const int* __restrict__ dst,
                      const float* __restrict__ X, const float* __restrict__ W,
                      unsigned* __restrict__ partial, uint2* __restrict__ Y,
                      int N, int E, int slice_d, int slice_s, int words) {
    __shared__ unsigned smem[SMEM_U32];
    int tid = (int)threadIdx.x;
    int b = (int)blockIdx.x;

    if (b < HB_D + HB_S) {
        // ---------------- histogram path (u8 packed: 4 nodes per u32) ----------------
        unsigned* h = smem;
        for (int w = tid; w < words; w += 1024) h[w] = 0u;
        __syncthreads();
        const int* __restrict__ keys;
        int sb, se;
        if (b < HB_D) { keys = dst; sb = b * slice_d; se = min(sb + slice_d, E); }
        else          { keys = src; sb = (b - HB_D) * slice_s; se = min(sb + slice_s, E); }
        for (int i = sb + tid * 4; i < se; i += 1024 * 4) {
            if (i + 3 < se) {
                int4 k4 = *reinterpret_cast<const int4*>(keys + i);
                atomicAdd(&h[k4.x >> 2], 1u << ((k4.x & 3) * 8));
                atomicAdd(&h[k4.y >> 2], 1u << ((k4.y & 3) * 8));
                atomicAdd(&h[k4.z >> 2], 1u << ((k4.z & 3) * 8));
                atomicAdd(&h[k4.w >> 2], 1u << ((k4.w & 3) * 8));
            } else {
                for (int j = i; j < se; ++j) {
                    int k = keys[j];
                    atomicAdd(&h[k >> 2], 1u << ((k & 3) * 8));
                }
            }
        }
        __syncthreads();
        unsigned* __restrict__ outp = partial + (size_t)b * words;
        for (int w = tid; w < words; w += 1024) outp[w] = h[w];
    } else {
        // ---------------- projection path: 4 nodes x 4 cols per thread ---------------
        float* w_s = (float*)smem;                                     // 8192 floats (32KB)
        for (int i = tid; i < IN_FEATS * OUT_FEATS / 4; i += 1024)
            reinterpret_cast<float4*>(w_s)[i] = reinterpret_cast<const float4*>(W)[i];
        __syncthreads();
        int slot = tid >> 4;                 // 0..63
        int jj = (tid & 15) * 4;             // col base
        int n0 = (b - (HB_D + HB_S)) * PROJ_NODES + slot * 4;
        // clamp load rows (only last block is partial; stores are guarded)
        int m0 = min(n0 + 0, N - 1), m1 = min(n0 + 1, N - 1);
        int m2 = min(n0 + 2, N - 1), m3 = min(n0 + 3, N - 1);
        const float* __restrict__ x0p = X + (size_t)m0 * IN_FEATS;
        const float* __restrict__ x1p = X + (size_t)m1 * IN_FEATS;
        const float* __restrict__ x2p = X + (size_t)m2 * IN_FEATS;
        const float* __restrict__ x3p = X + (size_t)m3 * IN_FEATS;
        float4 a0 = make_float4(0.f, 0.f, 0.f, 0.f), a1 = a0, a2 = a0, a3 = a0;
#pragma unroll 2
        for (int k = 0; k < IN_FEATS; k += 4) {
            float4 x0 = *reinterpret_cast<const float4*>(x0p + k);
            float4 x1 = *reinterpret_cast<const float4*>(x1p + k);
            float4 x2 = *reinterpret_cast<const float4*>(x2p + k);
            float4 x3 = *reinterpret_cast<const float4*>(x3p + k);
#pragma unroll
            for (int q = 0; q < 4; ++q) {
                float4 w = *reinterpret_cast<const float4*>(&w_s[(k + q) * OUT_FEATS + jj]);
                float e0 = (q == 0) ? x0.x : (q == 1) ? x0.y : (q == 2) ? x0.z : x0.w;
                float e1 = (q == 0) ? x1.x : (q == 1) ? x1.y : (q == 2) ? x1.z : x1.w;
                float e2 = (q == 0) ? x2.x : (q == 1) ? x2.y : (q == 2) ? x2.z : x2.w;
                float e3 = (q == 0) ? x3.x : (q == 1) ? x3.y : (q == 2) ? x3.z : x3.w;
                a0.x = fmaf(e0, w.x, a0.x); a0.y = fmaf(e0, w.y, a0.y);
                a0.z = fmaf(e0, w.z, a0.z); a0.w = fmaf(e0, w.w, a0.w);
                a1.x = fmaf(e1, w.x, a1.x); a1.y = fmaf(e1, w.y, a1.y);
                a1.z = fmaf(e1, w.z, a1.z); a1.w = fmaf(e1, w.w, a1.w);
                a2.x = fmaf(e2, w.x, a2.x); a2.y = fmaf(e2, w.y, a2.y);
                a2.z = fmaf(e2, w.z, a2.z); a2.w = fmaf(e2, w.w, a2.w);
                a3.x = fmaf(e3, w.x, a3.x); a3.y = fmaf(e3, w.y, a3.y);
                a3.z = fmaf(e3, w.z, a3.z); a3.w = fmaf(e3, w.w, a3.w);
            }
        }
        float4 accs[4] = {a0, a1, a2, a3};
#pragma unroll
        for (int i = 0; i < 4; ++i) {
            int node = n0 + i;
            if (node < N) {
                uint2 o;
                o.x = pack_bf16(accs[i].x, accs[i].y);
                o.y = pack_bf16(accs[i].z, accs[i].w);
                Y[(size_t)node * (OUT_FEATS / 4) + (jj >> 2)] = o;
            }
        }
    }
}

// ========== K2: per-word prefixes (register-batched, no inter-block deps) ==============
__global__ __launch_bounds__(PB)
void prefix_kernel(const unsigned* __restrict__ partial, unsigned* __restrict__ pprefix,
                   unsigned* __restrict__ cntDp, unsigned* __restrict__ cntSp,
                   int* __restrict__ bsums, int words) {
    __shared__ int red[PB];
    int tid = (int)threadIdx.x;
    int w = (int)blockIdx.x * PB + tid;
    int dtot = 0;
    if (w < words) {
        unsigned run = 0;
        for (int bb = 0; bb < HB_D; bb += 16) {
            unsigned v[16], pfx[16];
#pragma unroll
            for (int i = 0; i < 16; ++i) v[i] = partial[(size_t)(bb + i) * words + w];
#pragma unroll
            for (int i = 0; i < 16; ++i) { pfx[i] = run; run += v[i]; }
#pragma unroll
            for (int i = 0; i < 16; ++i) pprefix[(size_t)(bb + i) * words + w] = pfx[i];
        }
        unsigned ssum = 0;
        for (int bb = HB_D; bb < HB_D + HB_S; bb += 16) {
            unsigned v[16];
#pragma unroll
            for (int i = 0; i < 16; ++i) v[i] = partial[(size_t)(bb + i) * words + w];
#pragma unroll
            for (int i = 0; i < 16; ++i) ssum += v[i];
        }
        cntDp[w] = run;
        cntSp[w] = ssum;
        dtot = (int)((run & 0xffu) + ((run >> 8) & 0xffu) + ((run >> 16) & 0xffu) + (run >> 24));
    }
    red[tid] = dtot;
    __syncthreads();
    for (int off = PB / 2; off > 0; off >>= 1) {
        if (tid < off) red[tid] += red[tid + off];
        __syncthreads();
    }
    if (tid == 0) bsums[blockIdx.x] = red[0];
}

// ========== K3: rowptr + norms; wave0 re-scans the (<=64) chunk sums inline ============
__global__ __launch_bounds__(PB)
void scan_apply(const unsigned* __restrict__ cntDp, const unsigned* __restrict__ cntSp,
                const int* __restrict__ bsums, int* __restrict__ rowptr,
                float* __restrict__ normS, float* __restrict__ normD,
                int N, int words, int NB) {
    __shared__ int tsum[PB];
    __shared__ int sboff;
    int tid = (int)threadIdx.x;
    if (tid < 64) {                       // NB <= 64 by construction
        int v = (tid < NB) ? bsums[tid] : 0;
        int orig = v;
        for (int off = 1; off < 64; off <<= 1) {
            int t = __shfl_up(v, off);
            if (tid >= off) v += t;
        }
        if (tid == (int)blockIdx.x) sboff = v - orig;          // exclusive chunk base
        if (blockIdx.x == 0 && tid == NB - 1) rowptr[N] = v;   // grand total
    }
    __syncthreads();
    int w = (int)blockIdx.x * PB + tid;
    unsigned cd = (w < words) ? cntDp[w] : 0u;
    unsigned cs = (w < words) ? cntSp[w] : 0u;
    int c0 = (int)(cd & 0xffu), c1 = (int)((cd >> 8) & 0xffu);
    int c2 = (int)((cd >> 16) & 0xffu), c3 = (int)(cd >> 24);
    int dtot = c0 + c1 + c2 + c3;
    tsum[tid] = dtot;
    __syncthreads();
    for (int off = 1; off < PB; off <<= 1) {
        int t = (tid >= off) ? tsum[tid - off] : 0;
        __syncthreads();
        tsum[tid] += t;
        __syncthreads();
    }
    if (w < words) {
        int excl = tsum[tid] - dtot + sboff;
        int r0 = excl, r1 = r0 + c0, r2 = r1 + c1, r3 = r2 + c2;
        int base = 4 * w;
        if (base + 3 < N + 1) {
            *reinterpret_cast<int4*>(rowptr + base) = make_int4(r0, r1, r2, r3);
        } else {
            int r[4] = {r0, r1, r2, r3};
            for (int i = 0; i < 4 && base + i <= N; ++i) rowptr[base + i] = r[i];
        }
        float4 nD = make_float4(rsqrtf(fmaxf((float)c0, 1.f)), rsqrtf(fmaxf((float)c1, 1.f)),
                                rsqrtf(fmaxf((float)c2, 1.f)), rsqrtf(fmaxf((float)c3, 1.f)));
        int s0 = (int)(cs & 0xffu), s1 = (int)((cs >> 8) & 0xffu);
        int s2 = (int)((cs >> 16) & 0xffu), s3 = (int)(cs >> 24);
        float4 nS = make_float4(rsqrtf(fmaxf((float)s0, 1.f)), rsqrtf(fmaxf((float)s1, 1.f)),
                                rsqrtf(fmaxf((float)s2, 1.f)), rsqrtf(fmaxf((float)s3, 1.f)));
        if (base + 3 < N) {
            *reinterpret_cast<float4*>(normD + base) = nD;
            *reinterpret_cast<float4*>(normS + base) = nS;
        } else {
            float d[4] = {nD.x, nD.y, nD.z, nD.w};
            float s[4] = {nS.x, nS.y, nS.z, nS.w};
            for (int i = 0; i < 4 && base + i < N; ++i) { normD[base + i] = d[i]; normS[base + i] = s[i]; }
        }
    }
}

// ========== K4: CSR fill, u8 LDS cursors seeded from precomputed per-block prefixes ====
__global__ __launch_bounds__(1024)
void fill_kernel(const int* __restrict__ src, const int* __restrict__ dst,
                 const unsigned* __restrict__ pprefix, const int* __restrict__ rowptr,
                 int* __restrict__ csr_src, int E, int slice, int words) {
    __shared__ unsigned cur[MAX_WORDS];
    int tid = (int)threadIdx.x;
    int b = (int)blockIdx.x;
    const unsigned* __restrict__ pp = pprefix + (size_t)b * words;
    for (int w = tid; w < words; w += 1024) cur[w] = pp[w];
    __syncthreads();
    int sb = b * slice;
    int se = min(sb + slice, E);
    for (int i = sb + tid * 4; i < se; i += 1024 * 4) {
        if (i + 3 < se) {
            int4 d4 = *reinterpret_cast<const int4*>(dst + i);
            int4 s4 = *reinterpret_cast<const int4*>(src + i);
            int dd[4] = {d4.x, d4.y, d4.z, d4.w};
            int ss[4] = {s4.x, s4.y, s4.z, s4.w};
#pragma unroll
            for (int j = 0; j < 4; ++j) {
                int bin = dd[j];
                unsigned sh = (unsigned)(bin & 3) * 8u;
                unsigned old = atomicAdd(&cur[bin >> 2], 1u << sh);
                int off = (int)((old >> sh) & 0xffu);
                csr_src[rowptr[bin] + off] = ss[j];
            }
        } else {
            for (int j = i; j < se; ++j) {
                int bin = dst[j];
                unsigned sh = (unsigned)(bin & 3) * 8u;
                unsigned old = atomicAdd(&cur[bin >> 2], 1u << sh);
                int off = (int)((old >> sh) & 0xffu);
                csr_src[rowptr[bin] + off] = src[j];
            }
        }
    }
}

// ================= gather hop over bf16 rows ================
// one wave/node; 16 lanes x uint2 (4 bf16) cover 64 feats; 4 edge-groups, 2x unroll.
// EPI: 0 -> bf16 out; 1 -> *vec[node], bf16 out; 2 -> *vec[node]+bias, f32 out
template <int EPI>
__global__ __launch_bounds__(256)
void gather_hop(const uint2* __restrict__ Yin, const int* __restrict__ rowptr,
                const int* __restrict__ csr_src, void* __restrict__ Yout,
                const float* __restrict__ vec, const float* __restrict__ bias,
                int N) {
    int node = blockIdx.x * 4 + ((int)threadIdx.x >> 6);
    int lane = (int)threadIdx.x & 63;
    int g = lane >> 4;
    int ci = lane & 15;
    if (node >= N) return;
    int beg = rowptr[node];
    int end = rowptr[node + 1];
    float4 acc = make_float4(0.f, 0.f, 0.f, 0.f);
    float4 acc2 = make_float4(0.f, 0.f, 0.f, 0.f);
    int k = beg + g;
    for (; k + 4 < end; k += 8) {
        int s0 = csr_src[k];
        int s1 = csr_src[k + 4];
        uint2 v0 = Yin[(size_t)s0 * (OUT_FEATS / 4) + ci];
        uint2 v1 = Yin[(size_t)s1 * (OUT_FEATS / 4) + ci];
        acc.x += bf16_lo(v0.x); acc.y += bf16_hi(v0.x);
        acc.z += bf16_lo(v0.y); acc.w += bf16_hi(v0.y);
        acc2.x += bf16_lo(v1.x); acc2.y += bf16_hi(v1.x);
        acc2.z += bf16_lo(v1.y); acc2.w += bf16_hi(v1.y);
    }
    if (k < end) {
        uint2 v = Yin[(size_t)csr_src[k] * (OUT_FEATS / 4) + ci];
        acc.x += bf16_lo(v.x); acc.y += bf16_hi(v.x);
        acc.z += bf16_lo(v.y); acc.w += bf16_hi(v.y);
    }
    acc.x += acc2.x; acc.y += acc2.y; acc.z += acc2.z; acc.w += acc2.w;
    acc.x += __shfl_xor(acc.x, 16); acc.y += __shfl_xor(acc.y, 16);
    acc.z += __shfl_xor(acc.z, 16); acc.w += __shfl_xor(acc.w, 16);
    acc.x += __shfl_xor(acc.x, 32); acc.y += __shfl_xor(acc.y, 32);
    acc.z += __shfl_xor(acc.z, 32); acc.w += __shfl_xor(acc.w, 32);
    if (g == 0) {
        if (EPI == 1) {
            float sc = vec[node];
            acc.x *= sc; acc.y *= sc; acc.z *= sc; acc.w *= sc;
        }
        if (EPI == 2) {
            float sc = vec[node];
            float4 bb = *reinterpret_cast<const float4*>(bias + ci * 4);
            acc.x = fmaf(acc.x, sc, bb.x); acc.y = fmaf(acc.y, sc, bb.y);
            acc.z = fmaf(acc.z, sc, bb.z); acc.w = fmaf(acc.w, sc, bb.w);
            reinterpret_cast<float4*>(Yout)[(size_t)node * (OUT_FEATS / 4) + ci] = acc;
        } else {
            uint2 o;
            o.x = pack_bf16(acc.x, acc.y);
            o.y = pack_bf16(acc.z, acc.w);
            reinterpret_cast<uint2*>(Yout)[(size_t)node * (OUT_FEATS / 4) + ci] = o;
        }
    }
}

extern "C" void kernel_launch(void* const* d_in, const int* in_sizes, int n_in,
                              void* d_out, int out_size, void* d_ws, size_t ws_size,
                              hipStream_t stream) {
    const float* features = (const float*)d_in[0];
    const int*   src      = (const int*)d_in[1];
    const int*   dst      = (const int*)d_in[2];
    const float* weight   = (const float*)d_in[3];
    const float* bias     = (const float*)d_in[4];

    const int N = in_sizes[0] / IN_FEATS;   // 50000
    const int E = in_sizes[1];              // 640000
    const int words = (N + 3) / 4;          // 12500 (u8-packed)
    const int NB = (words + PB - 1) / PB;   // 49 chunks (<= 64)
    const int slice_d = (((E + HB_D - 1) / HB_D) + 3) & ~3;  // 5000
    const int slice_s = (((E + HB_S - 1) / HB_S) + 3) & ~3;  // 10000
    const int projBlocks = (N + PROJ_NODES - 1) / PROJ_NODES; // 196

    char* p = (char*)d_ws;
    float* normS   = (float*)p;  p = align_up(p + sizeof(float) * (N + 4), 256);
    float* normD   = (float*)p;  p = align_up(p + sizeof(float) * (N + 4), 256);
    uint2* y0      = (uint2*)p;  p = align_up(p + sizeof(uint2) * (size_t)N * (OUT_FEATS / 4), 256);
    uint2* y1      = (uint2*)p;  p = align_up(p + sizeof(uint2) * (size_t)N * (OUT_FEATS / 4), 256);
    int*   rowptr  = (int*)p;    p = align_up(p + sizeof(int) * (N + 8), 256);
    unsigned* cntDp = (unsigned*)p;  p = align_up(p + sizeof(unsigned) * (words + 4), 256);
    unsigned* cntSp = (unsigned*)p;  p = align_up(p + sizeof(unsigned) * (words + 4), 256);
    int*   bsums   = (int*)p;    p = align_up(p + sizeof(int) * 64, 256);
    int*   csr_src = (int*)p;    p = align_up(p + sizeof(int) * (size_t)E, 256);
    unsigned* partial = (unsigned*)p;  p = align_up(p + sizeof(unsigned) * (size_t)(HB_D + HB_S) * words, 256);
    unsigned* pprefix = (unsigned*)p;  p = align_up(p + sizeof(unsigned) * (size_t)HB_D * words, 256);

    float* out = (float*)d_out;

    // K1: u8 histograms (192 blocks) + projection (196 blocks), concurrent
    hist_proj_kernel<<<HB_D + HB_S + projBlocks, 1024, 0, stream>>>(
        src, dst, features, weight, partial, y0, N, E, slice_d, slice_s, words);
    // K2: per-word prefixes + packed counts + chunk sums (register-batched, no chaining)
    prefix_kernel<<<NB, PB, 0, stream>>>(partial, pprefix, cntDp, cntSp, bsums, words);
    // K3: rowptr + norms (inline wave0 re-scan of chunk sums)
    scan_apply<<<NB, PB, 0, stream>>>(cntDp, cntSp, bsums, rowptr, normS, normD, N, words, NB);
    // K4: CSR fill, zero global atomics
    fill_kernel<<<HB_D, 1024, 0, stream>>>(src, dst, pprefix, rowptr, csr_src, E, slice_d, words);

    const int hop_blocks = (N + 3) / 4;
    // hop 1: y1 = A y0                    (bf16 -> bf16)
    gather_hop<0><<<hop_blocks, 256, 0, stream>>>(y0, rowptr, csr_src, (void*)y1, nullptr, nullptr, N);
    // hop 2: y0 = normS .* (A y1)         (bf16 -> bf16)
    gather_hop<1><<<hop_blocks, 256, 0, stream>>>(y1, rowptr, csr_src, (void*)y0, normS, nullptr, N);
    // hop 3: out = normD .* (A y0) + bias (bf16 -> f32)
    gather_hop<2><<<hop_blocks, 256, 0, stream>>>(y0, rowptr, csr_src, (void*)out, normD, bias, N);
}

// Round 11
// 109.639 us; speedup vs baseline: 2.5061x; 1.1156x over previous
//
#include <hip/hip_runtime.h>
#include <hip/hip_bf16.h>

#define IN_FEATS 128
#define OUT_FEATS 64
#define HB_D 128          // dst histogram/fill slices
#define HB_S 64           // src histogram slices
#define PB 256            // prefix/scan block threads (PB words = 1024 nodes)
#define MAX_WORDS 12544   // >= (N+3)/4 for N=50000 (u8-packed histogram, 50KB LDS)
#define SMEM_U32 12544    // K1 union: max(hist 12500 u32, proj 8192 floats for W)
#define PROJ_NODES 256    // nodes per proj block (64 slots x 4 nodes)
#define HOP_BLOCKS 2048   // grid-stride hop blocks (8192 waves = full machine)

static inline char* align_up(char* p, size_t a) {
    return (char*)(((uintptr_t)p + a - 1) & ~(uintptr_t)(a - 1));
}

// ---- bf16 helpers (RNE pack, shift unpack; math always fp32) ----
__device__ __forceinline__ unsigned pack_bf16(float a, float b) {
    unsigned ua = __float_as_uint(a), ub = __float_as_uint(b);
    ua = (ua + 0x7fffu + ((ua >> 16) & 1u)) >> 16;
    ub = (ub + 0x7fffu + ((ub >> 16) & 1u)) >> 16;
    return ua | (ub << 16);
}
__device__ __forceinline__ float bf16_lo(unsigned u) { return __uint_as_float(u << 16); }
__device__ __forceinline__ float bf16_hi(unsigned u) { return __uint_as_float(u & 0xffff0000u); }

// ================= K1: fused histogram (192 blocks) + projection (196 blocks) ==========
// blocks [0, HB_D)         : u8-packed LDS histogram of dst slice b
// blocks [HB_D, HB_D+HB_S) : u8-packed LDS histogram of src slice b-HB_D
// blocks [HB_D+HB_S, ...)  : proj y0 = bf16(X @ W); 256 nodes/block, 4 nodes x 4 cols
// block 0 additionally zeroes the K2 allocation counter.
__global__ __launch_bounds__(1024)
void hist_proj_kernel(const int* __restrict__ src, const int* __restrict__ dst,
                      const float* __restrict__ X, const float* __restrict__ W,
                      unsigned* __restrict__ partial, uint2* __restrict__ Y,
                      int* __restrict__ gcounter,
                      int N, int E, int slice_d, int slice_s, int words) {
    __shared__ unsigned smem[SMEM_U32];
    int tid = (int)threadIdx.x;
    int b = (int)blockIdx.x;

    if (b == 0 && tid == 0) *gcounter = 0;   // K2 runs after K1 completes (stream order)

    if (b < HB_D + HB_S) {
        // ---------------- histogram path (u8 packed: 4 nodes per u32) ----------------
        unsigned* h = smem;
        for (int w = tid; w < words; w += 1024) h[w] = 0u;
        __syncthreads();
        const int* __restrict__ keys;
        int sb, se;
        if (b < HB_D) { keys = dst; sb = b * slice_d; se = min(sb + slice_d, E); }
        else          { keys = src; sb = (b - HB_D) * slice_s; se = min(sb + slice_s, E); }
        for (int i = sb + tid * 4; i < se; i += 1024 * 4) {
            if (i + 3 < se) {
                int4 k4 = *reinterpret_cast<const int4*>(keys + i);
                atomicAdd(&h[k4.x >> 2], 1u << ((k4.x & 3) * 8));
                atomicAdd(&h[k4.y >> 2], 1u << ((k4.y & 3) * 8));
                atomicAdd(&h[k4.z >> 2], 1u << ((k4.z & 3) * 8));
                atomicAdd(&h[k4.w >> 2], 1u << ((k4.w & 3) * 8));
            } else {
                for (int j = i; j < se; ++j) {
                    int k = keys[j];
                    atomicAdd(&h[k >> 2], 1u << ((k & 3) * 8));
                }
            }
        }
        __syncthreads();
        unsigned* __restrict__ outp = partial + (size_t)b * words;
        for (int w = tid; w < words; w += 1024) outp[w] = h[w];
    } else {
        // ---------------- projection path: 4 nodes x 4 cols per thread ---------------
        float* w_s = (float*)smem;                                     // 8192 floats (32KB)
        for (int i = tid; i < IN_FEATS * OUT_FEATS / 4; i += 1024)
            reinterpret_cast<float4*>(w_s)[i] = reinterpret_cast<const float4*>(W)[i];
        __syncthreads();
        int slot = tid >> 4;                 // 0..63
        int jj = (tid & 15) * 4;             // col base
        int n0 = (b - (HB_D + HB_S)) * PROJ_NODES + slot * 4;
        int m0 = min(n0 + 0, N - 1), m1 = min(n0 + 1, N - 1);
        int m2 = min(n0 + 2, N - 1), m3 = min(n0 + 3, N - 1);
        const float* __restrict__ x0p = X + (size_t)m0 * IN_FEATS;
        const float* __restrict__ x1p = X + (size_t)m1 * IN_FEATS;
        const float* __restrict__ x2p = X + (size_t)m2 * IN_FEATS;
        const float* __restrict__ x3p = X + (size_t)m3 * IN_FEATS;
        float4 a0 = make_float4(0.f, 0.f, 0.f, 0.f), a1 = a0, a2 = a0, a3 = a0;
#pragma unroll 2
        for (int k = 0; k < IN_FEATS; k += 4) {
            float4 x0 = *reinterpret_cast<const float4*>(x0p + k);
            float4 x1 = *reinterpret_cast<const float4*>(x1p + k);
            float4 x2 = *reinterpret_cast<const float4*>(x2p + k);
            float4 x3 = *reinterpret_cast<const float4*>(x3p + k);
#pragma unroll
            for (int q = 0; q < 4; ++q) {
                float4 w = *reinterpret_cast<const float4*>(&w_s[(k + q) * OUT_FEATS + jj]);
                float e0 = (q == 0) ? x0.x : (q == 1) ? x0.y : (q == 2) ? x0.z : x0.w;
                float e1 = (q == 0) ? x1.x : (q == 1) ? x1.y : (q == 2) ? x1.z : x1.w;
                float e2 = (q == 0) ? x2.x : (q == 1) ? x2.y : (q == 2) ? x2.z : x2.w;
                float e3 = (q == 0) ? x3.x : (q == 1) ? x3.y : (q == 2) ? x3.z : x3.w;
                a0.x = fmaf(e0, w.x, a0.x); a0.y = fmaf(e0, w.y, a0.y);
                a0.z = fmaf(e0, w.z, a0.z); a0.w = fmaf(e0, w.w, a0.w);
                a1.x = fmaf(e1, w.x, a1.x); a1.y = fmaf(e1, w.y, a1.y);
                a1.z = fmaf(e1, w.z, a1.z); a1.w = fmaf(e1, w.w, a1.w);
                a2.x = fmaf(e2, w.x, a2.x); a2.y = fmaf(e2, w.y, a2.y);
                a2.z = fmaf(e2, w.z, a2.z); a2.w = fmaf(e2, w.w, a2.w);
                a3.x = fmaf(e3, w.x, a3.x); a3.y = fmaf(e3, w.y, a3.y);
                a3.z = fmaf(e3, w.z, a3.z); a3.w = fmaf(e3, w.w, a3.w);
            }
        }
        float4 accs[4] = {a0, a1, a2, a3};
#pragma unroll
        for (int i = 0; i < 4; ++i) {
            int node = n0 + i;
            if (node < N) {
                uint2 o;
                o.x = pack_bf16(accs[i].x, accs[i].y);
                o.y = pack_bf16(accs[i].z, accs[i].w);
                Y[(size_t)node * (OUT_FEATS / 4) + (jj >> 2)] = o;
            }
        }
    }
}

// ========== K2: prefixes + atomic segment allocation + rowext/norms (fused) ============
// thread w: exclusive prefix of dst-partials across HB_D blocks -> pprefix; packed counts.
// Block claims a contiguous span with ONE atomicAdd (segment placement is arbitrary;
// per-node edge ORDER stays pprefix-deterministic, so output is bit-identical).
__global__ __launch_bounds__(PB)
void prefix_alloc_kernel(const unsigned* __restrict__ partial, unsigned* __restrict__ pprefix,
                         int2* __restrict__ rowext, float* __restrict__ normS,
                         float* __restrict__ normD, int* __restrict__ gcounter,
                         int N, int words) {
    __shared__ int tsum[PB];
    __shared__ int s_base;
    int tid = (int)threadIdx.x;
    int w = (int)blockIdx.x * PB + tid;
    unsigned run = 0, ssum = 0;
    if (w < words) {
        for (int bb = 0; bb < HB_D; bb += 16) {
            unsigned v[16], pfx[16];
#pragma unroll
            for (int i = 0; i < 16; ++i) v[i] = partial[(size_t)(bb + i) * words + w];
#pragma unroll
            for (int i = 0; i < 16; ++i) { pfx[i] = run; run += v[i]; }
#pragma unroll
            for (int i = 0; i < 16; ++i) pprefix[(size_t)(bb + i) * words + w] = pfx[i];
        }
        for (int bb = HB_D; bb < HB_D + HB_S; bb += 16) {
            unsigned v[16];
#pragma unroll
            for (int i = 0; i < 16; ++i) v[i] = partial[(size_t)(bb + i) * words + w];
#pragma unroll
            for (int i = 0; i < 16; ++i) ssum += v[i];
        }
    }
    int c0 = (int)(run & 0xffu), c1 = (int)((run >> 8) & 0xffu);
    int c2 = (int)((run >> 16) & 0xffu), c3 = (int)(run >> 24);
    int dtot = c0 + c1 + c2 + c3;
    tsum[tid] = dtot;
    __syncthreads();
    for (int off = 1; off < PB; off <<= 1) {
        int t = (tid >= off) ? tsum[tid - off] : 0;
        __syncthreads();
        tsum[tid] += t;
        __syncthreads();
    }
    if (tid == PB - 1) s_base = atomicAdd(gcounter, tsum[PB - 1]);  // claim span
    __syncthreads();
    if (w < words) {
        int excl = tsum[tid] - dtot + s_base;
        int r0 = excl, r1 = r0 + c0, r2 = r1 + c1, r3 = r2 + c2;
        int base = 4 * w;
        if (base + 3 < N) {
            int4* re = reinterpret_cast<int4*>(rowext + base);
            re[0] = make_int4(r0, r1, r1, r2);
            re[1] = make_int4(r2, r3, r3, r3 + c3);
            float4 nD = make_float4(rsqrtf(fmaxf((float)c0, 1.f)), rsqrtf(fmaxf((float)c1, 1.f)),
                                    rsqrtf(fmaxf((float)c2, 1.f)), rsqrtf(fmaxf((float)c3, 1.f)));
            int s0 = (int)(ssum & 0xffu), s1 = (int)((ssum >> 8) & 0xffu);
            int s2 = (int)((ssum >> 16) & 0xffu), s3 = (int)(ssum >> 24);
            float4 nS = make_float4(rsqrtf(fmaxf((float)s0, 1.f)), rsqrtf(fmaxf((float)s1, 1.f)),
                                    rsqrtf(fmaxf((float)s2, 1.f)), rsqrtf(fmaxf((float)s3, 1.f)));
            *reinterpret_cast<float4*>(normD + base) = nD;
            *reinterpret_cast<float4*>(normS + base) = nS;
        } else {
            int r[5] = {r0, r1, r2, r3, r3 + c3};
            int cD[4] = {c0, c1, c2, c3};
            int cS[4] = {(int)(ssum & 0xffu), (int)((ssum >> 8) & 0xffu),
                         (int)((ssum >> 16) & 0xffu), (int)(ssum >> 24)};
            for (int i = 0; i < 4 && base + i < N; ++i) {
                rowext[base + i] = make_int2(r[i], r[i + 1]);
                normD[base + i] = rsqrtf(fmaxf((float)cD[i], 1.f));
                normS[base + i] = rsqrtf(fmaxf((float)cS[i], 1.f));
            }
        }
    }
}

// ========== K3: CSR fill (u16 ids), u8 LDS cursors seeded from per-block prefixes ======
__global__ __launch_bounds__(1024)
void fill_kernel(const int* __restrict__ src, const int* __restrict__ dst,
                 const unsigned* __restrict__ pprefix, const int2* __restrict__ rowext,
                 unsigned short* __restrict__ csr16, int E, int slice, int words) {
    __shared__ unsigned cur[MAX_WORDS];
    int tid = (int)threadIdx.x;
    int b = (int)blockIdx.x;
    const unsigned* __restrict__ pp = pprefix + (size_t)b * words;
    for (int w = tid; w < words; w += 1024) cur[w] = pp[w];
    __syncthreads();
    int sb = b * slice;
    int se = min(sb + slice, E);
    for (int i = sb + tid * 4; i < se; i += 1024 * 4) {
        if (i + 3 < se) {
            int4 d4 = *reinterpret_cast<const int4*>(dst + i);
            int4 s4 = *reinterpret_cast<const int4*>(src + i);
            int dd[4] = {d4.x, d4.y, d4.z, d4.w};
            int ss[4] = {s4.x, s4.y, s4.z, s4.w};
#pragma unroll
            for (int j = 0; j < 4; ++j) {
                int bin = dd[j];
                unsigned sh = (unsigned)(bin & 3) * 8u;
                unsigned old = atomicAdd(&cur[bin >> 2], 1u << sh);
                int off = (int)((old >> sh) & 0xffu);
                csr16[rowext[bin].x + off] = (unsigned short)ss[j];
            }
        } else {
            for (int j = i; j < se; ++j) {
                int bin = dst[j];
                unsigned sh = (unsigned)(bin & 3) * 8u;
                unsigned old = atomicAdd(&cur[bin >> 2], 1u << sh);
                int off = (int)((old >> sh) & 0xffu);
                csr16[rowext[bin].x + off] = (unsigned short)src[j];
            }
        }
    }
}

// ================= gather hop over bf16 rows (grid-stride, u16 csr) ================
// one wave/node per iteration; 16 lanes x uint2 (4 bf16) cover 64 feats; 4 edge-groups.
// EPI: 0 -> bf16 out; 1 -> *vec[node], bf16 out; 2 -> *vec[node]+bias, f32 out
template <int EPI>
__global__ __launch_bounds__(256)
void gather_hop(const uint2* __restrict__ Yin, const int2* __restrict__ rowext,
                const unsigned short* __restrict__ csr16, void* __restrict__ Yout,
                const float* __restrict__ vec, const float* __restrict__ bias,
                int N) {
    int lane = (int)threadIdx.x & 63;
    int g = lane >> 4;
    int ci = lane & 15;
    int gwave = (int)blockIdx.x * 4 + ((int)threadIdx.x >> 6);
    int nwaves = (int)gridDim.x * 4;
    for (int node = gwave; node < N; node += nwaves) {
        int2 be = rowext[node];
        int beg = be.x, end = be.y;
        float4 acc = make_float4(0.f, 0.f, 0.f, 0.f);
        float4 acc2 = make_float4(0.f, 0.f, 0.f, 0.f);
        int k = beg + g;
        for (; k + 4 < end; k += 8) {
            int s0 = (int)csr16[k];
            int s1 = (int)csr16[k + 4];
            uint2 v0 = Yin[(size_t)s0 * (OUT_FEATS / 4) + ci];
            uint2 v1 = Yin[(size_t)s1 * (OUT_FEATS / 4) + ci];
            acc.x += bf16_lo(v0.x); acc.y += bf16_hi(v0.x);
            acc.z += bf16_lo(v0.y); acc.w += bf16_hi(v0.y);
            acc2.x += bf16_lo(v1.x); acc2.y += bf16_hi(v1.x);
            acc2.z += bf16_lo(v1.y); acc2.w += bf16_hi(v1.y);
        }
        if (k < end) {
            uint2 v = Yin[(size_t)csr16[k] * (OUT_FEATS / 4) + ci];
            acc.x += bf16_lo(v.x); acc.y += bf16_hi(v.x);
            acc.z += bf16_lo(v.y); acc.w += bf16_hi(v.y);
        }
        acc.x += acc2.x; acc.y += acc2.y; acc.z += acc2.z; acc.w += acc2.w;
        acc.x += __shfl_xor(acc.x, 16); acc.y += __shfl_xor(acc.y, 16);
        acc.z += __shfl_xor(acc.z, 16); acc.w += __shfl_xor(acc.w, 16);
        acc.x += __shfl_xor(acc.x, 32); acc.y += __shfl_xor(acc.y, 32);
        acc.z += __shfl_xor(acc.z, 32); acc.w += __shfl_xor(acc.w, 32);
        if (g == 0) {
            if (EPI == 1) {
                float sc = vec[node];
                acc.x *= sc; acc.y *= sc; acc.z *= sc; acc.w *= sc;
            }
            if (EPI == 2) {
                float sc = vec[node];
                float4 bb = *reinterpret_cast<const float4*>(bias + ci * 4);
                acc.x = fmaf(acc.x, sc, bb.x); acc.y = fmaf(acc.y, sc, bb.y);
                acc.z = fmaf(acc.z, sc, bb.z); acc.w = fmaf(acc.w, sc, bb.w);
                reinterpret_cast<float4*>(Yout)[(size_t)node * (OUT_FEATS / 4) + ci] = acc;
            } else {
                uint2 o;
                o.x = pack_bf16(acc.x, acc.y);
                o.y = pack_bf16(acc.z, acc.w);
                reinterpret_cast<uint2*>(Yout)[(size_t)node * (OUT_FEATS / 4) + ci] = o;
            }
        }
    }
}

extern "C" void kernel_launch(void* const* d_in, const int* in_sizes, int n_in,
                              void* d_out, int out_size, void* d_ws, size_t ws_size,
                              hipStream_t stream) {
    const float* features = (const float*)d_in[0];
    const int*   src      = (const int*)d_in[1];
    const int*   dst      = (const int*)d_in[2];
    const float* weight   = (const float*)d_in[3];
    const float* bias     = (const float*)d_in[4];

    const int N = in_sizes[0] / IN_FEATS;   // 50000 (node ids fit u16)
    const int E = in_sizes[1];              // 640000
    const int words = (N + 3) / 4;          // 12500 (u8-packed)
    const int NB = (words + PB - 1) / PB;   // 49 chunks
    const int slice_d = (((E + HB_D - 1) / HB_D) + 3) & ~3;  // 5000
    const int slice_s = (((E + HB_S - 1) / HB_S) + 3) & ~3;  // 10000
    const int projBlocks = (N + PROJ_NODES - 1) / PROJ_NODES; // 196

    char* p = (char*)d_ws;
    float* normS   = (float*)p;  p = align_up(p + sizeof(float) * (N + 4), 256);
    float* normD   = (float*)p;  p = align_up(p + sizeof(float) * (N + 4), 256);
    uint2* y0      = (uint2*)p;  p = align_up(p + sizeof(uint2) * (size_t)N * (OUT_FEATS / 4), 256);
    uint2* y1      = (uint2*)p;  p = align_up(p + sizeof(uint2) * (size_t)N * (OUT_FEATS / 4), 256);
    int2*  rowext  = (int2*)p;   p = align_up(p + sizeof(int2) * (N + 4), 256);
    int*   gcounter= (int*)p;    p = align_up(p + sizeof(int) * 4, 256);
    unsigned short* csr16 = (unsigned short*)p;  p = align_up(p + sizeof(unsigned short) * (size_t)E, 256);
    unsigned* partial = (unsigned*)p;  p = align_up(p + sizeof(unsigned) * (size_t)(HB_D + HB_S) * words, 256);
    unsigned* pprefix = (unsigned*)p;  p = align_up(p + sizeof(unsigned) * (size_t)HB_D * words, 256);

    float* out = (float*)d_out;

    // K1: u8 histograms (192 blocks) + projection (196 blocks), concurrent
    hist_proj_kernel<<<HB_D + HB_S + projBlocks, 1024, 0, stream>>>(
        src, dst, features, weight, partial, y0, gcounter, N, E, slice_d, slice_s, words);
    // K2: prefixes + atomic segment allocation + rowext/norms (one kernel)
    prefix_alloc_kernel<<<NB, PB, 0, stream>>>(partial, pprefix, rowext, normS, normD,
                                               gcounter, N, words);
    // K3: CSR fill (u16), zero global atomics
    fill_kernel<<<HB_D, 1024, 0, stream>>>(src, dst, pprefix, rowext, csr16, E, slice_d, words);

    const int hop_blocks = min((N + 3) / 4, HOP_BLOCKS);
    // hop 1: y1 = A y0                    (bf16 -> bf16)
    gather_hop<0><<<hop_blocks, 256, 0, stream>>>(y0, rowext, csr16, (void*)y1, nullptr, nullptr, N);
    // hop 2: y0 = normS .* (A y1)         (bf16 -> bf16)
    gather_hop<1><<<hop_blocks, 256, 0, stream>>>(y1, rowext, csr16, (void*)y0, normS, nullptr, N);
    // hop 3: out = normD .* (A y0) + bias (bf16 -> f32)
    gather_hop<2><<<hop_blocks, 256, 0, stream>>>(y0, rowext, csr16, (void*)out, normD, bias, N);
}